// Round 3
// baseline (546.958 us; speedup 1.0000x reference)
//
#include <hip/hip_runtime.h>
#include <hip/hip_bf16.h>

// Problem constants: B=32, S=4096, E=512, D=512, H=512
#define BATCH 32
#define SEQ   4096
#define EDIM  512
#define HDIM  512

typedef unsigned short u16;
typedef unsigned int   u32;

typedef __bf16 bf16x8 __attribute__((ext_vector_type(8)));
typedef float  f32x4  __attribute__((ext_vector_type(4)));

__device__ __forceinline__ u16 bf_rne(float x) {
    u32 u = __float_as_uint(x);
    u32 r = (u + 0x7fffu + ((u >> 16) & 1u)) >> 16;   // round-to-nearest-even
    return (u16)r;
}
__device__ __forceinline__ u32 pack2(u16 lo, u16 hi) {
    return (u32)lo | ((u32)hi << 16);
}
__device__ __forceinline__ float tanh_fast(float x) {
    float e = __builtin_amdgcn_exp2f(x * 2.88539008177793f);
    return 1.0f - 2.0f * __builtin_amdgcn_rcpf(e + 1.0f);
}

// ---------------------------------------------------------------------------
// prep_kernel: fuses (a) dec_bias = dec @ W_dec^T + b_dec + b_enc  [blocks 0..4095]
//                    (b) pack W_enc fp32 -> bf16 b-fragment layout  [blocks 4096..4223]
//                    (c) zero d_out                                  [block 4224]
// wpack chunk id = (nsub*16 + kc)*64 + lane;
// lane holds W[nsub*16+(l&15)][kc*32+(l>>4)*8+j], j=0..7
// ---------------------------------------------------------------------------
__global__ void prep_kernel(const float* __restrict__ W_enc, uint4* __restrict__ wpack,
                            const float* __restrict__ dec, const float* __restrict__ Wd,
                            const float* __restrict__ b_enc, const float* __restrict__ b_dec,
                            float* __restrict__ dec_bias, float* __restrict__ out) {
    int bid = blockIdx.x;
    int t = threadIdx.x;
    if (bid < 4096) {
        int wave = t >> 6, lane = t & 63;
        int p = bid * 4 + wave;
        int b = p >> 9, h = p & 511;
        const float4* wr = reinterpret_cast<const float4*>(Wd)  + h * 128;
        const float4* dr = reinterpret_cast<const float4*>(dec) + b * 128;
        float4 w0 = wr[lane * 2], w1 = wr[lane * 2 + 1];
        float4 d0 = dr[lane * 2], d1 = dr[lane * 2 + 1];
        float s = w0.x * d0.x + w0.y * d0.y + w0.z * d0.z + w0.w * d0.w
                + w1.x * d1.x + w1.y * d1.y + w1.z * d1.z + w1.w * d1.w;
#pragma unroll
        for (int m = 1; m < 64; m <<= 1) s += __shfl_xor(s, m, 64);
        if (lane == 0) dec_bias[p] = s + b_dec[h] + b_enc[h];
    } else if (bid < 4224) {
        int id   = (bid - 4096) * 256 + t;          // 32768 chunks
        int nsub = id >> 10;
        int rem  = id & 1023;
        int kc   = rem >> 6;
        int lane = rem & 63;
        int row  = nsub * 16 + (lane & 15);
        int col  = kc * 32 + (lane >> 4) * 8;
        const float* src = W_enc + row * EDIM + col;
        uint4 o;
        o.x = pack2(bf_rne(src[0]), bf_rne(src[1]));
        o.y = pack2(bf_rne(src[2]), bf_rne(src[3]));
        o.z = pack2(bf_rne(src[4]), bf_rne(src[5]));
        o.w = pack2(bf_rne(src[6]), bf_rne(src[7]));
        wpack[id] = o;
    } else {
        float4 z = make_float4(0.f, 0.f, 0.f, 0.f);
        float4* o4 = reinterpret_cast<float4*>(out);
#pragma unroll
        for (int i = 0; i < 16; i++) o4[i * 256 + t] = z;   // 32*512 floats
    }
}

// ---------------------------------------------------------------------------
// Kernel 2 v3: fused enc-projection + tanh + v-dot -> scores[131072]
// M=128 tile, 512 thr (8 waves = 2 m-halves x 4 n-slices of 128), BK=64 phases.
// ONE barrier/phase. Issue order per phase: 16 B-frag L2 loads FIRST, then 4
// X-prefetch HBM loads (vmcnt FIFO: B waits then never force X drain), compute
// 2 ksteps, cvt+write prefetch to other LDS buffer, barrier (drains loads
// issued a full phase earlier).
// LDS A: bf16, row stride 72 u16 (144 B): ds_read_b128 optimal 8 dwords/bank.
// mfma_f32_16x16x32_bf16: A[m=l&15][k=(l>>4)*8+j]; C/D: m=(l>>4)*4+r, n=l&15.
// ---------------------------------------------------------------------------
__global__ __launch_bounds__(512, 2) void score_kernel(
    const float* __restrict__ X, const uint4* __restrict__ Wp,
    const float* __restrict__ bias, const float* __restrict__ v,
    float* __restrict__ scores)
{
    __shared__ alignas(16) u16 Abuf[2][128 * 72];   // 36 KB
    __shared__ float sred[8][64];

    const int tid  = threadIdx.x;
    const int wave = tid >> 6, lane = tid & 63;
    const int quad = lane >> 4, l15 = lane & 15;
    const int mh = wave >> 2;          // m-half (rows mh*64 .. mh*64+63)
    const int ns = wave & 3;           // n-slice (cols ns*128 .. ns*128+127)
    const int blk = blockIdx.x;        // 1024 blocks
    const long row0 = (long)blk * 128;
    const int b = blk >> 5;            // 32 m-blocks per batch
    const float4* X4 = reinterpret_cast<const float4*>(X + row0 * EDIM);

    f32x4 acc[4][8] = {};              // [msub][nsub]

    // staging map: phase tile = 128 rows x 64 floats; thread: row r, 4 float4
    const int r = tid >> 2;            // 0..127
    const int s = tid & 3;             // float4 group

    // ---- prologue: stage phase 0 ----
    {
        float4 p0[4];
#pragma unroll
        for (int i = 0; i < 4; i++) p0[i] = X4[r * 128 + s * 4 + i];
#pragma unroll
        for (int i = 0; i < 4; i++) {
            uint2 w = make_uint2(pack2(bf_rne(p0[i].x), bf_rne(p0[i].y)),
                                 pack2(bf_rne(p0[i].z), bf_rne(p0[i].w)));
            *reinterpret_cast<uint2*>(&Abuf[0][r * 72 + (s * 4 + i) * 4]) = w;
        }
    }
    __syncthreads();

#pragma unroll 2
    for (int ph = 0; ph < 8; ph++) {
        const int cur = ph & 1;
        const u16* Ab = Abuf[cur];

        // (1) B fragments for both ksteps — issued FIRST (L2-resident wpack)
        uint4 braw[16];
#pragma unroll
        for (int ks = 0; ks < 2; ks++)
#pragma unroll
            for (int jj = 0; jj < 8; jj++)
                braw[ks * 8 + jj] = Wp[((ns * 8 + jj) * 16 + ph * 2 + ks) * 64 + lane];

        // (2) X prefetch for next phase — issued AFTER braw, consumed at phase end
        float4 pf[4];
        if (ph < 7) {
#pragma unroll
            for (int i = 0; i < 4; i++)
                pf[i] = X4[r * 128 + (ph + 1) * 16 + s * 4 + i];
        }

        // (3) compute 2 ksteps
#pragma unroll
        for (int ks = 0; ks < 2; ks++) {
            bf16x8 af[4];
#pragma unroll
            for (int i = 0; i < 4; i++)
                af[i] = *reinterpret_cast<const bf16x8*>(
                    &Ab[(mh * 64 + i * 16 + l15) * 72 + ks * 32 + quad * 8]);
#pragma unroll
            for (int jj = 0; jj < 8; jj++) {
                bf16x8 bfr = __builtin_bit_cast(bf16x8, braw[ks * 8 + jj]);
#pragma unroll
                for (int i = 0; i < 4; i++)
                    acc[i][jj] = __builtin_amdgcn_mfma_f32_16x16x32_bf16(
                        af[i], bfr, acc[i][jj], 0, 0, 0);
            }
        }

        // (4) stage prefetch into the other buffer
        if (ph < 7) {
#pragma unroll
            for (int i = 0; i < 4; i++) {
                uint2 w = make_uint2(pack2(bf_rne(pf[i].x), bf_rne(pf[i].y)),
                                     pack2(bf_rne(pf[i].z), bf_rne(pf[i].w)));
                *reinterpret_cast<uint2*>(&Abuf[cur ^ 1][r * 72 + (s * 4 + i) * 4]) = w;
            }
        }
        __syncthreads();   // single barrier per phase
    }

    // ---- epilogue ----
    float hb[8], hv[8];
#pragma unroll
    for (int jj = 0; jj < 8; jj++) {
        int h = ns * 128 + jj * 16 + l15;
        hb[jj] = bias[b * HDIM + h];
        hv[jj] = v[h];
    }

    float s_acc[16];
#pragma unroll
    for (int x = 0; x < 16; x++) s_acc[x] = 0.f;
#pragma unroll
    for (int i = 0; i < 4; i++)
#pragma unroll
        for (int jj = 0; jj < 8; jj++)
#pragma unroll
            for (int rr = 0; rr < 4; rr++)
                s_acc[i * 4 + rr] += hv[jj] * tanh_fast(acc[i][jj][rr] + hb[jj]);

#pragma unroll
    for (int m = 1; m < 16; m <<= 1)
#pragma unroll
        for (int x = 0; x < 16; x++)
            s_acc[x] += __shfl_xor(s_acc[x], m, 16);

    if (l15 == 0) {
#pragma unroll
        for (int x = 0; x < 16; x++) {
            int i = x >> 2, rr = x & 3;
            sred[wave][i * 16 + quad * 4 + rr] = s_acc[x];
        }
    }
    __syncthreads();
    if (tid < 128) {
        int mhh = tid >> 6, m = tid & 63;
        scores[row0 + tid] = sred[mhh * 4 + 0][m] + sred[mhh * 4 + 1][m]
                           + sred[mhh * 4 + 2][m] + sred[mhh * 4 + 3][m];
    }
}

// ---------------------------------------------------------------------------
// Kernel 3: softmax over S per batch.
// ---------------------------------------------------------------------------
__global__ void softmax_k(const float* __restrict__ scores, float* __restrict__ attn) {
    __shared__ float redmax[4], redsum[4];
    int b = blockIdx.x, t = threadIdx.x;
    int wave = t >> 6, lane = t & 63;
    const float* sb = scores + b * SEQ;
    float vals[16];
    float mx = -1e30f;
#pragma unroll
    for (int i = 0; i < 16; i++) { vals[i] = sb[i * 256 + t]; mx = fmaxf(mx, vals[i]); }
#pragma unroll
    for (int m = 1; m < 64; m <<= 1) mx = fmaxf(mx, __shfl_xor(mx, m, 64));
    if (lane == 0) redmax[wave] = mx;
    __syncthreads();
    mx = fmaxf(fmaxf(redmax[0], redmax[1]), fmaxf(redmax[2], redmax[3]));
    float s = 0.f;
#pragma unroll
    for (int i = 0; i < 16; i++) {
        float e = __builtin_amdgcn_exp2f((vals[i] - mx) * 1.44269504088896f);
        vals[i] = e; s += e;
    }
#pragma unroll
    for (int m = 1; m < 64; m <<= 1) s += __shfl_xor(s, m, 64);
    if (lane == 0) redsum[wave] = s;
    __syncthreads();
    s = redsum[0] + redsum[1] + redsum[2] + redsum[3];
    float inv = 1.0f / s;
    float* ab = attn + b * SEQ;
#pragma unroll
    for (int i = 0; i < 16; i++) ab[i * 256 + t] = vals[i] * inv;
}

// ---------------------------------------------------------------------------
// Kernel 4: context[b][e] = sum_s attn[b][s] * X[b][s][e].
// 2048 blocks (b x 64-seq chunks), batched loads, split accumulators.
// ---------------------------------------------------------------------------
__global__ __launch_bounds__(256) void context_k(const float* __restrict__ X,
                                                 const float* __restrict__ attn,
                                                 float* __restrict__ out) {
    __shared__ float aw[64];
    int blk = blockIdx.x;
    int b = blk >> 6, s0 = (blk & 63) << 6;
    int t = threadIdx.x;
    if (t < 64) aw[t] = attn[b * SEQ + s0 + t];
    __syncthreads();
    const float2* Xp = reinterpret_cast<const float2*>(X) + ((long)(b * SEQ + s0)) * 256 + t;
    float ax0 = 0.f, ay0 = 0.f, ax1 = 0.f, ay1 = 0.f;
#pragma unroll 4
    for (int s = 0; s < 64; s += 8) {
        float2 x[8];
#pragma unroll
        for (int k = 0; k < 8; k++) x[k] = Xp[(long)(s + k) * 256];
#pragma unroll
        for (int k = 0; k < 8; k += 2) {
            float w0 = aw[s + k], w1 = aw[s + k + 1];
            ax0 = fmaf(w0, x[k].x,     ax0);
            ay0 = fmaf(w0, x[k].y,     ay0);
            ax1 = fmaf(w1, x[k + 1].x, ax1);
            ay1 = fmaf(w1, x[k + 1].y, ay1);
        }
    }
    atomicAdd(&out[b * EDIM + t * 2],     ax0 + ax1);
    atomicAdd(&out[b * EDIM + t * 2 + 1], ay0 + ay1);
}

// ---------------------------------------------------------------------------
extern "C" void kernel_launch(void* const* d_in, const int* in_sizes, int n_in,
                              void* d_out, int out_size, void* d_ws, size_t ws_size,
                              hipStream_t stream) {
    const float* X      = (const float*)d_in[0];
    const float* dec    = (const float*)d_in[1];
    const float* W_enc  = (const float*)d_in[2];
    const float* b_enc  = (const float*)d_in[3];
    const float* W_dec  = (const float*)d_in[4];
    const float* b_dec  = (const float*)d_in[5];
    const float* v      = (const float*)d_in[6];
    float* out = (float*)d_out;

    char* ws = (char*)d_ws;
    uint4* wpack    = (uint4*)ws;                                 // 512 KB
    float* dec_bias = (float*)(ws + (512 << 10));                 // 64 KB
    float* scores   = (float*)(ws + (512 << 10) + (64 << 10));    // 512 KB
    float* attn     = (float*)(ws + (1024 << 10) + (64 << 10));   // 512 KB

    prep_kernel <<<4225, 256, 0, stream>>>(W_enc, wpack, dec, W_dec, b_enc, b_dec,
                                           dec_bias, out);
    score_kernel<<<1024, 512, 0, stream>>>(X, wpack, dec_bias, v, scores);
    softmax_k   <<<32,   256, 0, stream>>>(scores, attn);
    context_k   <<<2048, 256, 0, stream>>>(X, attn, out);
}

// Round 4
// 447.525 us; speedup vs baseline: 1.2222x; 1.2222x over previous
//
#include <hip/hip_runtime.h>
#include <hip/hip_bf16.h>

// Problem constants: B=32, S=4096, E=512, D=512, H=512
#define BATCH 32
#define SEQ   4096
#define EDIM  512
#define HDIM  512
#define NCHUNK 64                 // S-chunks of 64 rows per batch
#define NBLK  (BATCH * NCHUNK)    // 2048 fused blocks

typedef unsigned short u16;
typedef unsigned int   u32;

typedef __bf16 bf16x8 __attribute__((ext_vector_type(8)));
typedef float  f32x4  __attribute__((ext_vector_type(4)));

__device__ __forceinline__ u16 bf_rne(float x) {
    u32 u = __float_as_uint(x);
    u32 r = (u + 0x7fffu + ((u >> 16) & 1u)) >> 16;   // round-to-nearest-even
    return (u16)r;
}
__device__ __forceinline__ u32 pack2(u16 lo, u16 hi) {
    return (u32)lo | ((u32)hi << 16);
}
__device__ __forceinline__ float tanh_fast(float x) {
    float e = __builtin_amdgcn_exp2f(x * 2.88539008177793f);
    return 1.0f - 2.0f * __builtin_amdgcn_rcpf(e + 1.0f);
}

// ---------------------------------------------------------------------------
// prep_kernel: (a) dec_bias = dec @ W_dec^T + b_dec + b_enc   [blocks 0..4095]
//              (b) pack W_enc fp32 -> bf16 b-fragment layout  [blocks 4096..4223]
// wpack chunk id = (nsub*16 + kc)*64 + lane;
// lane holds W[nsub*16+(l&15)][kc*32+(l>>4)*8+j], j=0..7
// ---------------------------------------------------------------------------
__global__ void prep_kernel(const float* __restrict__ W_enc, uint4* __restrict__ wpack,
                            const float* __restrict__ dec, const float* __restrict__ Wd,
                            const float* __restrict__ b_enc, const float* __restrict__ b_dec,
                            float* __restrict__ dec_bias) {
    int bid = blockIdx.x;
    int t = threadIdx.x;
    if (bid < 4096) {
        int wave = t >> 6, lane = t & 63;
        int p = bid * 4 + wave;
        int b = p >> 9, h = p & 511;
        const float4* wr = reinterpret_cast<const float4*>(Wd)  + h * 128;
        const float4* dr = reinterpret_cast<const float4*>(dec) + b * 128;
        float4 w0 = wr[lane * 2], w1 = wr[lane * 2 + 1];
        float4 d0 = dr[lane * 2], d1 = dr[lane * 2 + 1];
        float s = w0.x * d0.x + w0.y * d0.y + w0.z * d0.z + w0.w * d0.w
                + w1.x * d1.x + w1.y * d1.y + w1.z * d1.z + w1.w * d1.w;
#pragma unroll
        for (int m = 1; m < 64; m <<= 1) s += __shfl_xor(s, m, 64);
        if (lane == 0) dec_bias[p] = s + b_dec[h] + b_enc[h];
    } else {
        int id   = (bid - 4096) * 256 + t;          // 32768 chunks
        int nsub = id >> 10;
        int rem  = id & 1023;
        int kc   = rem >> 6;
        int lane = rem & 63;
        int row  = nsub * 16 + (lane & 15);
        int col  = kc * 32 + (lane >> 4) * 8;
        const float* src = W_enc + row * EDIM + col;
        uint4 o;
        o.x = pack2(bf_rne(src[0]), bf_rne(src[1]));
        o.y = pack2(bf_rne(src[2]), bf_rne(src[3]));
        o.z = pack2(bf_rne(src[4]), bf_rne(src[5]));
        o.w = pack2(bf_rne(src[6]), bf_rne(src[7]));
        wpack[id] = o;
    }
}

// ---------------------------------------------------------------------------
// fused_kernel: per block = (batch b, 64-row S-chunk).
//  Phase A: GEMM enc_hs = X_tile @ W_enc^T (bf16 MFMA), tanh, v-dot -> 64 scores
//           K-loop: BK=32 x 16 chunks, double-buffered LDS, ONE barrier/chunk.
//           Issue order: braw[8] (L2) FIRST, then X prefetch for ch+2 (HBM) —
//           vmcnt FIFO: MFMA's wait on braw never drains the younger X loads,
//           so X stays in flight ~2 iterations (>= HBM latency).
//  Phase B: local softmax over the 64 scores (m_loc, p_i, l_loc).
//  Phase C: c_loc[512] = sum_i p_i * X_tile[i][:]  (X re-read, L2-hot).
//  Writes (m_loc, l_loc, c_loc) partials; combine_k merges 64 chunks/batch.
// mfma_f32_16x16x32_bf16: A[m=l&15][k=(l>>4)*8+j]; C/D: m=(l>>4)*4+r, n=l&15.
// LDS A row stride 72 u16: both ds_write_b128 and ds_read_b128 hit all 32
// banks evenly (8 dwords/bank = optimal).
// ---------------------------------------------------------------------------
__global__ __launch_bounds__(256, 2) void fused_kernel(
    const float* __restrict__ X, const uint4* __restrict__ Wp,
    const float* __restrict__ bias, const float* __restrict__ v,
    float* __restrict__ cpart, float* __restrict__ mpart, float* __restrict__ lpart)
{
    __shared__ alignas(16) u16 Abuf[2][64 * 72];   // 18 KB
    __shared__ float sred[4][64];
    __shared__ float pbuf[64];

    const int tid  = threadIdx.x;
    const int wave = tid >> 6, lane = tid & 63;
    const int quad = lane >> 4, l15 = lane & 15;
    const int blk  = blockIdx.x;          // 2048
    const int b    = blk >> 6;
    const long row0 = (long)blk * 64;
    const float4* X4 = reinterpret_cast<const float4*>(X + row0 * EDIM);

    f32x4 acc[4][8] = {};                 // [msub][nsub]: m=64, n=128 per wave

    // staging map: chunk = 64 rows x 32 floats; thread: row r, 8 consecutive floats
    const int r  = tid >> 2;              // 0..63
    const int c8 = tid & 3;               // which 8-float group

    // ---- prologue: load+stage chunk 0, preload chunk 1 ----
    float4 pA = X4[r * 128 + c8 * 2];
    float4 pB = X4[r * 128 + c8 * 2 + 1];
    {
        uint4 w;
        w.x = pack2(bf_rne(pA.x), bf_rne(pA.y));
        w.y = pack2(bf_rne(pA.z), bf_rne(pA.w));
        w.z = pack2(bf_rne(pB.x), bf_rne(pB.y));
        w.w = pack2(bf_rne(pB.z), bf_rne(pB.w));
        *reinterpret_cast<uint4*>(&Abuf[0][r * 72 + c8 * 8]) = w;
    }
    pA = X4[r * 128 + 8 + c8 * 2];
    pB = X4[r * 128 + 8 + c8 * 2 + 1];
    __syncthreads();

    for (int ch = 0; ch < 16; ch++) {
        const u16* Ab = Abuf[ch & 1];

        // (1) B fragments for this chunk — issued FIRST (L2-resident)
        uint4 braw[8];
#pragma unroll
        for (int jj = 0; jj < 8; jj++)
            braw[jj] = Wp[((wave * 8 + jj) * 16 + ch) * 64 + lane];

        // (2) X prefetch for chunk ch+2 — younger than braw in the vm FIFO
        float4 nA, nB;
        if (ch < 14) {
            nA = X4[r * 128 + (ch + 2) * 8 + c8 * 2];
            nB = X4[r * 128 + (ch + 2) * 8 + c8 * 2 + 1];
        }

        // (3) MFMA (waits braw + ds_read only)
        bf16x8 af[4];
#pragma unroll
        for (int i = 0; i < 4; i++)
            af[i] = *reinterpret_cast<const bf16x8*>(&Ab[(i * 16 + l15) * 72 + quad * 8]);
#pragma unroll
        for (int jj = 0; jj < 8; jj++) {
            bf16x8 bfr = __builtin_bit_cast(bf16x8, braw[jj]);
#pragma unroll
            for (int i = 0; i < 4; i++)
                acc[i][jj] = __builtin_amdgcn_mfma_f32_16x16x32_bf16(
                    af[i], bfr, acc[i][jj], 0, 0, 0);
        }

        // (4) stage chunk ch+1 (in pA/pB, loaded one full iteration ago)
        if (ch < 15) {
            uint4 w;
            w.x = pack2(bf_rne(pA.x), bf_rne(pA.y));
            w.y = pack2(bf_rne(pA.z), bf_rne(pA.w));
            w.z = pack2(bf_rne(pB.x), bf_rne(pB.y));
            w.w = pack2(bf_rne(pB.z), bf_rne(pB.w));
            *reinterpret_cast<uint4*>(&Abuf[(ch & 1) ^ 1][r * 72 + c8 * 8]) = w;
        }
        __syncthreads();
        if (ch < 14) { pA = nA; pB = nB; }
    }

    // ---- epilogue: scores ----
    float hb[8], hv[8];
#pragma unroll
    for (int jj = 0; jj < 8; jj++) {
        int h = wave * 128 + jj * 16 + l15;
        hb[jj] = bias[b * HDIM + h];
        hv[jj] = v[h];
    }
    float s_acc[16];
#pragma unroll
    for (int x = 0; x < 16; x++) s_acc[x] = 0.f;
#pragma unroll
    for (int i = 0; i < 4; i++)
#pragma unroll
        for (int jj = 0; jj < 8; jj++)
#pragma unroll
            for (int rr = 0; rr < 4; rr++)
                s_acc[i * 4 + rr] += hv[jj] * tanh_fast(acc[i][jj][rr] + hb[jj]);

#pragma unroll
    for (int m = 1; m < 16; m <<= 1)
#pragma unroll
        for (int x = 0; x < 16; x++)
            s_acc[x] += __shfl_xor(s_acc[x], m, 16);

    if (l15 == 0) {
#pragma unroll
        for (int x = 0; x < 16; x++) {
            int i = x >> 2, rr = x & 3;
            sred[wave][i * 16 + quad * 4 + rr] = s_acc[x];
        }
    }
    __syncthreads();

    // ---- phase B: local softmax over 64 scores (wave 0) ----
    if (tid < 64) {
        float sc = sred[0][tid] + sred[1][tid] + sred[2][tid] + sred[3][tid];
        float mx = sc;
#pragma unroll
        for (int m = 1; m < 64; m <<= 1) mx = fmaxf(mx, __shfl_xor(mx, m, 64));
        float p = __builtin_amdgcn_exp2f((sc - mx) * 1.44269504088896f);
        float l = p;
#pragma unroll
        for (int m = 1; m < 64; m <<= 1) l += __shfl_xor(l, m, 64);
        pbuf[tid] = p;
        if (tid == 0) { mpart[blk] = mx; lpart[blk] = l; }
    }
    __syncthreads();

    // ---- phase C: weighted sum of X tile (L2-hot re-read) ----
    const float2* Xp = reinterpret_cast<const float2*>(X + row0 * EDIM) + tid;
    float ax0 = 0.f, ay0 = 0.f, ax1 = 0.f, ay1 = 0.f;
#pragma unroll 2
    for (int s = 0; s < 64; s += 8) {
        float2 x[8];
#pragma unroll
        for (int k = 0; k < 8; k++) x[k] = Xp[(s + k) * 256];
#pragma unroll
        for (int k = 0; k < 8; k += 2) {
            float w0 = pbuf[s + k], w1 = pbuf[s + k + 1];
            ax0 = fmaf(w0, x[k].x,     ax0);
            ay0 = fmaf(w0, x[k].y,     ay0);
            ax1 = fmaf(w1, x[k + 1].x, ax1);
            ay1 = fmaf(w1, x[k + 1].y, ay1);
        }
    }
    reinterpret_cast<float2*>(cpart)[blk * 256 + tid] =
        make_float2(ax0 + ax1, ay0 + ay1);
}

// ---------------------------------------------------------------------------
// combine_k: per batch, merge 64 chunk partials (flash-decoding style).
// out[b][e] = sum_i exp(m_i - M) * c_i[e] / sum_i exp(m_i - M) * l_i
// ---------------------------------------------------------------------------
__global__ __launch_bounds__(256) void combine_k(const float* __restrict__ cpart,
                                                 const float* __restrict__ mpart,
                                                 const float* __restrict__ lpart,
                                                 float* __restrict__ out) {
    __shared__ float wbuf[64];
    __shared__ float linv_s;
    int b = blockIdx.x, t = threadIdx.x;
    if (t < 64) {
        float m = mpart[b * 64 + t];
        float M = m;
#pragma unroll
        for (int k = 1; k < 64; k <<= 1) M = fmaxf(M, __shfl_xor(M, k, 64));
        float w = __builtin_amdgcn_exp2f((m - M) * 1.44269504088896f);
        float lw = lpart[b * 64 + t] * w;
        float L = lw;
#pragma unroll
        for (int k = 1; k < 64; k <<= 1) L += __shfl_xor(L, k, 64);
        wbuf[t] = w;
        if (t == 0) linv_s = 1.0f / L;
    }
    __syncthreads();
    const float2* cp = reinterpret_cast<const float2*>(cpart) + (long)b * 64 * 256 + t;
    float ax = 0.f, ay = 0.f;
#pragma unroll 2
    for (int i = 0; i < 64; i += 8) {
        float2 x[8];
#pragma unroll
        for (int k = 0; k < 8; k++) x[k] = cp[(i + k) * 256];
#pragma unroll
        for (int k = 0; k < 8; k++) {
            float w = wbuf[i + k];
            ax = fmaf(w, x[k].x, ax);
            ay = fmaf(w, x[k].y, ay);
        }
    }
    float inv = linv_s;
    reinterpret_cast<float2*>(out)[b * 256 + t] = make_float2(ax * inv, ay * inv);
}

// ---------------------------------------------------------------------------
extern "C" void kernel_launch(void* const* d_in, const int* in_sizes, int n_in,
                              void* d_out, int out_size, void* d_ws, size_t ws_size,
                              hipStream_t stream) {
    const float* X      = (const float*)d_in[0];
    const float* dec    = (const float*)d_in[1];
    const float* W_enc  = (const float*)d_in[2];
    const float* b_enc  = (const float*)d_in[3];
    const float* W_dec  = (const float*)d_in[4];
    const float* b_dec  = (const float*)d_in[5];
    const float* v      = (const float*)d_in[6];
    float* out = (float*)d_out;

    char* ws = (char*)d_ws;
    uint4* wpack    = (uint4*)ws;                          // 512 KB
    float* dec_bias = (float*)(ws + (512 << 10));          // 64 KB
    float* cpart    = (float*)(ws + (576 << 10));          // 2048*512*4 = 4 MB
    float* mpart    = (float*)(ws + (576 << 10) + (4096 << 10));   // 8 KB
    float* lpart    = (float*)(ws + (576 << 10) + (4104 << 10));   // 8 KB

    prep_kernel  <<<4224, 256, 0, stream>>>(W_enc, wpack, dec, W_dec, b_enc, b_dec,
                                            dec_bias);
    fused_kernel <<<NBLK, 256, 0, stream>>>(X, wpack, dec_bias, v, cpart, mpart, lpart);
    combine_k    <<<BATCH, 256, 0, stream>>>(cpart, mpart, lpart, out);
}